// Round 4
// baseline (208.381 us; speedup 1.0000x reference)
//
#include <hip/hip_runtime.h>
#include <stdint.h>

// Problem constants (reference: B,T,D=4,4096,1024; E,C,O=8,1024,512)
#define Bdim 4
#define Tdim 4096
#define Ddim 1024
#define Edim 8
#define Cdim 1024
#define Odim 512

using bf16x8 = __attribute__((ext_vector_type(8))) __bf16;
using f32x4  = __attribute__((ext_vector_type(4))) float;

// round-to-nearest-even f32 -> bf16 (inputs finite; no NaN handling needed)
__device__ __forceinline__ unsigned short f2bf(float f) {
  unsigned int u = __float_as_uint(f);
  u += 0x7fffu + ((u >> 16) & 1u);
  return (unsigned short)(u >> 16);
}

// Single merged cast: [0,nx4) from x, [nx4,ntot4) from w.
__global__ void cast_f32_to_bf16(const float* __restrict__ xin,
                                 const float* __restrict__ win,
                                 unsigned short* __restrict__ outp,
                                 int nx4, int ntot4) {
  int i = blockIdx.x * blockDim.x + threadIdx.x;
  if (i >= ntot4) return;
  float4 v;
  if (i < nx4) v = reinterpret_cast<const float4*>(xin)[i];
  else         v = reinterpret_cast<const float4*>(win)[i - nx4];
  ushort4 o;
  o.x = f2bf(v.x); o.y = f2bf(v.y); o.z = f2bf(v.z); o.w = f2bf(v.w);
  reinterpret_cast<ushort4*>(outp)[i] = o;
}

// async global->LDS, 16B per lane; LDS dest is wave-uniform base (HW adds
// lane*16B).
__device__ __forceinline__ void async_copy16(const unsigned short* g,
                                             unsigned short* l) {
  __builtin_amdgcn_global_load_lds(
      (__attribute__((address_space(1))) unsigned int*)g,
      (__attribute__((address_space(3))) unsigned int*)l, 16, 0, 0);
}

// R3 structure: one block = 128x128 tile of one (b,e) GEMM, 4 waves 2x2,
// 4x4 accs of mfma_f32_16x16x32_bf16, BK=64.
//  - A (gathered tokens): NO LDS. Each lane loads its MFMA A-fragment
//    (16B, k-contiguous) straight from global into VGPRs, prefetched one
//    K-iter ahead. Removes half the LDS traffic (R2 accounting: LDS pipe
//    ~30us of 57us) and decouples random-gather latency from the barrier.
//  - B (weights): global_load_lds double-buffer (2x16KiB), XOR-swizzled
//    (R1, verified conflicts=0), coalesced rows -> L2-friendly; prefetch
//    covered by a full compute phase. One barrier per iter.
__global__ __launch_bounds__(256) void moe_mfma_gemm(
    const unsigned short* __restrict__ xbf,   // (B,T,D) bf16
    const unsigned short* __restrict__ wbf,   // (E,O,D) bf16
    const int* __restrict__ idx,              // (B,E,C)
    const float* __restrict__ bias,           // (E,O)
    float* __restrict__ out) {                // (B,E,C,O) f32
  __shared__ __align__(16) unsigned short sB[2][128 * 64];
  __shared__ int sTok[128];

  const int bid = blockIdx.x;
  const int be = bid >> 5;        // 0..31  (b*E+e)
  const int mt = (bid >> 2) & 7;  // 0..7   M tile
  const int nt = bid & 3;         // 0..3   N tile
  const int b = be >> 3;
  const int e = be & 7;

  const int tid = threadIdx.x;
  const int lane = tid & 63;
  const int wid = tid >> 6;
  const int wm = wid >> 1;  // 0..1
  const int wn = wid & 1;   // 0..1

  if (tid < 128) sTok[tid] = idx[be * Cdim + mt * 128 + tid];
  __syncthreads();

  const int fr = lane & 15;    // fragment m/n index
  const int fkc = lane >> 4;   // fragment k-chunk (0..3)
  const int sw = fr & 7;       // read-side XOR swizzle

  // Per-lane A fragment bases: row = gathered token, k-offset = fkc*8.
  const unsigned short* gAf[4];
#pragma unroll
  for (int im = 0; im < 4; ++im) {
    const int row = wm * 64 + im * 16 + fr;
    gAf[im] = xbf + ((size_t)(b * Tdim + sTok[row])) * Ddim + fkc * 8;
  }

  // B staging: 4 global_load_lds per wave per tile (32 rows/wave).
  const int rsub = lane >> 3;                  // row within 8-row group
  const int kcol = (((lane & 7) ^ rsub) * 8);  // swizzled element offset
  const unsigned short* gB[4];
#pragma unroll
  for (int i = 0; i < 4; ++i) {
    const int r = wid * 32 + i * 8 + rsub;  // tile row 0..127 (r&7 == rsub)
    gB[i] = wbf + ((size_t)(e * Odim + nt * 128 + r)) * Ddim + kcol;
  }
  const int ldsOff = (wid * 32) * 64;

  f32x4 acc[4][4];
#pragma unroll
  for (int im = 0; im < 4; ++im)
#pragma unroll
    for (int in = 0; in < 4; ++in) acc[im][in] = (f32x4){0.f, 0.f, 0.f, 0.f};

  // Prefetch B tile 0 into buffer 0.
#pragma unroll
  for (int i = 0; i < 4; ++i) async_copy16(gB[i], &sB[0][ldsOff + i * 8 * 64]);

  // Prefetch A fragments for iter 0 (global -> VGPR, no barrier dependency).
  bf16x8 afN[2][4];
#pragma unroll
  for (int kb = 0; kb < 2; ++kb)
#pragma unroll
    for (int im = 0; im < 4; ++im)
      afN[kb][im] = *(const bf16x8*)(gAf[im] + kb * 32);

#pragma unroll
  for (int k0 = 0; k0 < 16; ++k0) {
    const int cur = k0 & 1;
    __syncthreads();  // drains B tile-k0 prefetch + A frags for k0

    // Prefetch B tile k0+1 into alt buffer.
    if (k0 < 15) {
      const int koff = (k0 + 1) * 64;
#pragma unroll
      for (int i = 0; i < 4; ++i)
        async_copy16(gB[i] + koff, &sB[cur ^ 1][ldsOff + i * 8 * 64]);
    }

    bf16x8 afC[2][4];
#pragma unroll
    for (int kb = 0; kb < 2; ++kb)
#pragma unroll
      for (int im = 0; im < 4; ++im) afC[kb][im] = afN[kb][im];

    // Prefetch A fragments for iter k0+1 (covered by this iter's compute;
    // the next barrier's vmcnt(0) completes them, which is what we want).
    if (k0 < 15) {
      const int koff = (k0 + 1) * 64;
#pragma unroll
      for (int kb = 0; kb < 2; ++kb)
#pragma unroll
        for (int im = 0; im < 4; ++im)
          afN[kb][im] = *(const bf16x8*)(gAf[im] + koff + kb * 32);
    }

#pragma unroll
    for (int kb = 0; kb < 2; ++kb) {
      const int ko = ((kb * 4 + fkc) ^ sw) * 8;  // swizzled element offset
      bf16x8 bfr[4];
#pragma unroll
      for (int in = 0; in < 4; ++in)
        bfr[in] = *(const bf16x8*)&sB[cur][(size_t)(wn * 64 + in * 16 + fr) * 64 + ko];
#pragma unroll
      for (int im = 0; im < 4; ++im)
#pragma unroll
        for (int in = 0; in < 4; ++in)
          acc[im][in] = __builtin_amdgcn_mfma_f32_16x16x32_bf16(
              afC[kb][im], bfr[in], acc[im][in], 0, 0, 0);
    }
  }

  // Epilogue. C/D layout (verified m89/m91): col = lane&15 (n), row = (lane>>4)*4 + reg (m).
  float bv[4];
#pragma unroll
  for (int in = 0; in < 4; ++in)
    bv[in] = bias[e * Odim + nt * 128 + wn * 64 + in * 16 + fr];

  const int crow0 = (lane >> 4) * 4;
  float* outBase = out + (size_t)be * (Cdim * Odim) + (size_t)(mt * 128) * Odim + nt * 128;
#pragma unroll
  for (int im = 0; im < 4; ++im) {
    float* pr = outBase + (size_t)(wm * 64 + im * 16 + crow0) * Odim;
#pragma unroll
    for (int in = 0; in < 4; ++in) {
      float* p = pr + wn * 64 + in * 16 + fr;
#pragma unroll
      for (int r = 0; r < 4; ++r) p[(size_t)r * Odim] = acc[im][in][r] + bv[in];
    }
  }
}

extern "C" void kernel_launch(void* const* d_in, const int* in_sizes, int n_in,
                              void* d_out, int out_size, void* d_ws, size_t ws_size,
                              hipStream_t stream) {
  const float* x = (const float*)d_in[0];       // (B,T,D) f32
  const int* idx = (const int*)d_in[1];         // (B,E,C) i32
  const float* w = (const float*)d_in[2];       // (E,O,D) f32
  const float* bias = (const float*)d_in[3];    // (E,O) f32
  float* out = (float*)d_out;

  // Workspace: x_bf16 (32 MiB) then w_bf16 (8 MiB), contiguous
  unsigned short* xbf = (unsigned short*)d_ws;
  unsigned short* wbf = xbf + (size_t)Bdim * Tdim * Ddim;

  const int nx4 = Bdim * Tdim * Ddim / 4;               // 4,194,304
  const int ntot4 = nx4 + Edim * Odim * Ddim / 4;       // 5,242,880
  cast_f32_to_bf16<<<(ntot4 + 255) / 256, 256, 0, stream>>>(x, w, xbf, nx4, ntot4);

  // 32 (b,e) pairs x 8 M-tiles x 4 N-tiles = 1024 blocks
  moe_mfma_gemm<<<1024, 256, 0, stream>>>(xbf, wbf, idx, bias, out);
}

// Round 5
// 169.179 us; speedup vs baseline: 1.2317x; 1.2317x over previous
//
#include <hip/hip_runtime.h>
#include <stdint.h>

// Problem constants (reference: B,T,D=4,4096,1024; E,C,O=8,1024,512)
#define Bdim 4
#define Tdim 4096
#define Ddim 1024
#define Edim 8
#define Cdim 1024
#define Odim 512

using bf16x8 = __attribute__((ext_vector_type(8))) __bf16;
using f32x4  = __attribute__((ext_vector_type(4))) float;

// round-to-nearest-even f32 -> bf16 (inputs finite; no NaN handling needed)
__device__ __forceinline__ unsigned short f2bf(float f) {
  unsigned int u = __float_as_uint(f);
  u += 0x7fffu + ((u >> 16) & 1u);
  return (unsigned short)(u >> 16);
}

// Single merged cast: [0,nx4) from x, [nx4,ntot4) from w.
__global__ void cast_f32_to_bf16(const float* __restrict__ xin,
                                 const float* __restrict__ win,
                                 unsigned short* __restrict__ outp,
                                 int nx4, int ntot4) {
  int i = blockIdx.x * blockDim.x + threadIdx.x;
  if (i >= ntot4) return;
  float4 v;
  if (i < nx4) v = reinterpret_cast<const float4*>(xin)[i];
  else         v = reinterpret_cast<const float4*>(win)[i - nx4];
  ushort4 o;
  o.x = f2bf(v.x); o.y = f2bf(v.y); o.z = f2bf(v.z); o.w = f2bf(v.w);
  reinterpret_cast<ushort4*>(outp)[i] = o;
}

// async global->LDS, 16B per lane; LDS dest is wave-uniform base (HW adds
// lane*16B). Global address is per-lane -> gather + swizzle friendly.
__device__ __forceinline__ void async_copy16(const unsigned short* g,
                                             unsigned short* l) {
  __builtin_amdgcn_global_load_lds(
      (__attribute__((address_space(1))) unsigned int*)g,
      (__attribute__((address_space(3))) unsigned int*)l, 16, 0, 0);
}

// R4 = R1 structure (best: 55us; single-buffer BK=64, 2 barriers/iter,
// XOR-swizzled LDS, conflicts=0, 33KiB -> 4 blocks/CU, all 1024 blocks
// co-resident) + XCD-AWARE GRID SWIZZLE:
//   blockIdx round-robins across the 8 XCDs (bid%8 = XCD heuristic), so
//   decode e = bid&7  -> each XCD serves ONE expert: its 1 MiB weight
//   slice fits the 4 MiB L2 (was: every expert's weights streamed through
//   every XCD), and the 4 nt-blocks of each (be,mt) are slot-adjacent on
//   the SAME XCD -> the shared 128 gathered A-rows are L2-fetched once,
//   not 4x on 4 different XCDs. R1's FETCH=100MB (~2.5x ideal) and the
//   fully-exposed ~900cyc gather latency at each barrier drain are the
//   stall; this cuts both.
// R3 lesson: A staging must remain global_load_lds row-copies (per-lane
// fragment gather = 16-line scatter per instr, issue-bound, 88us).
__global__ __launch_bounds__(256) void moe_mfma_gemm(
    const unsigned short* __restrict__ xbf,   // (B,T,D) bf16
    const unsigned short* __restrict__ wbf,   // (E,O,D) bf16
    const int* __restrict__ idx,              // (B,E,C)
    const float* __restrict__ bias,           // (E,O)
    float* __restrict__ out) {                // (B,E,C,O) f32
  __shared__ __align__(16) unsigned short sA[128 * 64];
  __shared__ __align__(16) unsigned short sB[128 * 64];
  __shared__ int sTok[128];

  // XCD-aware decode: e fastest (XCD = e), then nt, mt, b.
  const int bid = blockIdx.x;
  const int e = bid & 7;
  const int r = bid >> 3;         // 0..127
  const int nt = r & 3;           // 0..3   N tile (slot-adjacent per (be,mt))
  const int mt = (r >> 2) & 7;    // 0..7   M tile
  const int b = r >> 5;           // 0..3
  const int be = b * 8 + e;

  const int tid = threadIdx.x;
  const int lane = tid & 63;
  const int wid = tid >> 6;
  const int wm = wid >> 1;  // 0..1
  const int wn = wid & 1;   // 0..1

  if (tid < 128) sTok[tid] = idx[be * Cdim + mt * 128 + tid];
  __syncthreads();

  // Staging: per wave, 4 global_load_lds per matrix per tile; each covers
  // 8 rows x 64 bf16. Lane loads global k-chunk ((lane&7) ^ rsub) of its row.
  const int rsub = lane >> 3;                       // row within 8-row group
  const int kcol = (((lane & 7) ^ rsub) * 8);       // swizzled element offset
  const unsigned short* gA[4];
  const unsigned short* gB[4];
#pragma unroll
  for (int i = 0; i < 4; ++i) {
    const int rr = wid * 32 + i * 8 + rsub;  // tile row 0..127 (rr&7 == rsub)
    gA[i] = xbf + ((size_t)(b * Tdim + sTok[rr])) * Ddim + kcol;       // gathered token
    gB[i] = wbf + ((size_t)(e * Odim + nt * 128 + rr)) * Ddim + kcol;  // weight row
  }

  f32x4 acc[4][4];
#pragma unroll
  for (int im = 0; im < 4; ++im)
#pragma unroll
    for (int in = 0; in < 4; ++in) acc[im][in] = (f32x4){0.f, 0.f, 0.f, 0.f};

  const int fr = lane & 15;    // fragment m/n index
  const int fkc = lane >> 4;   // fragment k-chunk (0..3) within 32-k block
  const int sw = fr & 7;       // read-side XOR (== row&7 for 16-aligned tiles)

  for (int k0 = 0; k0 < Ddim; k0 += 64) {
#pragma unroll
    for (int i = 0; i < 4; ++i) {
      async_copy16(gA[i] + k0, &sA[(wid * 32 + i * 8) * 64]);
      async_copy16(gB[i] + k0, &sB[(wid * 32 + i * 8) * 64]);
    }
    __syncthreads();  // drains vmcnt for global_load_lds
#pragma unroll
    for (int kb = 0; kb < 2; ++kb) {
      const int ko = ((kb * 4 + fkc) ^ sw) * 8;  // swizzled element offset in row
      bf16x8 af[4], bfr[4];
#pragma unroll
      for (int im = 0; im < 4; ++im)
        af[im] = *(const bf16x8*)&sA[(size_t)(wm * 64 + im * 16 + fr) * 64 + ko];
#pragma unroll
      for (int in = 0; in < 4; ++in)
        bfr[in] = *(const bf16x8*)&sB[(size_t)(wn * 64 + in * 16 + fr) * 64 + ko];
#pragma unroll
      for (int im = 0; im < 4; ++im)
#pragma unroll
        for (int in = 0; in < 4; ++in)
          acc[im][in] = __builtin_amdgcn_mfma_f32_16x16x32_bf16(
              af[im], bfr[in], acc[im][in], 0, 0, 0);
    }
    __syncthreads();
  }

  // Epilogue. C/D layout (verified m89/m91): col = lane&15 (n), row = (lane>>4)*4 + reg (m).
  float bv[4];
#pragma unroll
  for (int in = 0; in < 4; ++in)
    bv[in] = bias[e * Odim + nt * 128 + wn * 64 + in * 16 + fr];

  const int crow0 = (lane >> 4) * 4;
  float* outBase = out + (size_t)be * (Cdim * Odim) + (size_t)(mt * 128) * Odim + nt * 128;
#pragma unroll
  for (int im = 0; im < 4; ++im) {
    float* pr = outBase + (size_t)(wm * 64 + im * 16 + crow0) * Odim;
#pragma unroll
    for (int in = 0; in < 4; ++in) {
      float* p = pr + wn * 64 + in * 16 + fr;
#pragma unroll
      for (int r4 = 0; r4 < 4; ++r4) p[(size_t)r4 * Odim] = acc[im][in][r4] + bv[in];
    }
  }
}

extern "C" void kernel_launch(void* const* d_in, const int* in_sizes, int n_in,
                              void* d_out, int out_size, void* d_ws, size_t ws_size,
                              hipStream_t stream) {
  const float* x = (const float*)d_in[0];       // (B,T,D) f32
  const int* idx = (const int*)d_in[1];         // (B,E,C) i32
  const float* w = (const float*)d_in[2];       // (E,O,D) f32
  const float* bias = (const float*)d_in[3];    // (E,O) f32
  float* out = (float*)d_out;

  // Workspace: x_bf16 (32 MiB) then w_bf16 (8 MiB), contiguous
  unsigned short* xbf = (unsigned short*)d_ws;
  unsigned short* wbf = xbf + (size_t)Bdim * Tdim * Ddim;

  const int nx4 = Bdim * Tdim * Ddim / 4;               // 4,194,304
  const int ntot4 = nx4 + Edim * Odim * Ddim / 4;       // 5,242,880
  cast_f32_to_bf16<<<(ntot4 + 255) / 256, 256, 0, stream>>>(x, w, xbf, nx4, ntot4);

  // 32 (b,e) pairs x 8 M-tiles x 4 N-tiles = 1024 blocks, XCD-swizzled
  moe_mfma_gemm<<<1024, 256, 0, stream>>>(xbf, wbf, idx, bias, out);
}